// Round 3
// baseline (584.100 us; speedup 1.0000x reference)
//
#include <hip/hip_runtime.h>
#include <cfloat>
#include <cmath>

#define B_    4
#define SNIP  8
#define CCH   256
#define HW    784
#define THW   6272      // SNIP*HW
#define NROWS 25088     // B_*THW
#define TOPK  5
#define NTILE 49        // 6272/128
#define NPAIR 1225      // 49*50/2

typedef _Float16 f16;
typedef f16   half8 __attribute__((ext_vector_type(8)));
typedef f16   half4 __attribute__((ext_vector_type(4)));
typedef float f32x4 __attribute__((ext_vector_type(4)));

// ---------------------------------------------------------------- utilities
__device__ __forceinline__ void ins5(float key, int idx, float tv[TOPK], int ti[TOPK]) {
    if (key > tv[4]) {
        if (key > tv[2]) {
            if (key > tv[1]) {
                tv[4] = tv[3]; ti[4] = ti[3];
                tv[3] = tv[2]; ti[3] = ti[2];
                tv[2] = tv[1]; ti[2] = ti[1];
                if (key > tv[0]) { tv[1] = tv[0]; ti[1] = ti[0]; tv[0] = key; ti[0] = idx; }
                else             { tv[1] = key;  ti[1] = idx; }
            } else {
                tv[4] = tv[3]; ti[4] = ti[3];
                tv[3] = tv[2]; ti[3] = ti[2];
                tv[2] = key;   ti[2] = idx;
            }
        } else {
            if (key > tv[3]) { tv[4] = tv[3]; ti[4] = ti[3]; tv[3] = key; ti[3] = idx; }
            else             { tv[4] = key;  ti[4] = idx; }
        }
    }
}

__device__ __forceinline__ void async16(const void* g, void* l) {
    __builtin_amdgcn_global_load_lds(
        (const __attribute__((address_space(1))) void*)g,
        (__attribute__((address_space(3))) void*)l, 16, 0, 0);
}

// ------------------------------------------------- 1. fused transpose + rownorm + NORMALIZED f16 split
__global__ __launch_bounds__(256)
void transpose_norm_split_kernel(const float* __restrict__ x, f16* __restrict__ Xs,
                                 float* __restrict__ nrm) {
    __shared__ float T[256][33];
    const int bs = blockIdx.x;
    const int p0 = blockIdx.y * 32;
    const int b = bs >> 3, f = bs & 7;
    const int tid = threadIdx.x;

    const int pl = tid & 31, ch = tid >> 5;
    const int p = p0 + pl;
    if (p < HW) {
#pragma unroll
        for (int cc = 0; cc < 32; ++cc) {
            const int c = cc * 8 + ch;
            T[c][pl] = x[((size_t)bs * CCH + c) * HW + p];
        }
    }
    __syncthreads();

    const int rloc = tid >> 3, k = tid & 7;
    const int gp = p0 + rloc;
    const size_t trow = (size_t)b * THW + (size_t)f * HW + gp;

    float s = 0.0f;
    if (gp < HW) {
#pragma unroll
        for (int j = 0; j < 32; ++j) {
            const float v = T[k * 32 + j][rloc];
            s += v * v;
        }
    }
    s += __shfl_xor(s, 1, 64);
    s += __shfl_xor(s, 2, 64);
    s += __shfl_xor(s, 4, 64);

    if (gp < HW) {
        const float sq = sqrtf(s);
        const float rs = 1.0f / sq;
        if (k == 0) nrm[trow] = sq;
#pragma unroll
        for (int q = 0; q < 4; ++q) {
            half8 hv, lv;
#pragma unroll
            for (int j = 0; j < 8; ++j) {
                const float v = T[k * 32 + q * 8 + j][rloc] * rs;
                const f16 h = (f16)v;
                hv[j] = h;
                lv[j] = (f16)(v - (float)h);
            }
            *(half8*)(Xs + trow * 512 + k * 32 + q * 8) = hv;
            *(half8*)(Xs + trow * 512 + 256 + k * 32 + q * 8) = lv;
        }
    }
}

// ------------------------------------------------- 2a. block-level top5 merge + SoA partial store
__device__ __forceinline__ void block_merge_store(
    const float (*tv)[TOPK], const int (*ti)[TOPK], char* smem,
    int tid, int wid, int q, int wc, int lm,
    int rslot, size_t gcol0,
    float* __restrict__ pval, unsigned short* __restrict__ pidx) {
    float* Mv = (float*)smem;                              // [40][132] f32 = 21120 B
    unsigned short* Mi = (unsigned short*)(smem + 21120);  // [40][132] u16 = 10560 B
    const int slot = (wid >> 1) * 4 + q;
    __syncthreads();                                       // previous smem use done
#pragma unroll
    for (int j = 0; j < 4; ++j) {
        const int c128 = wc + 16 * j + lm;
#pragma unroll
        for (int s = 0; s < TOPK; ++s) {
            Mv[(slot * TOPK + s) * 132 + c128] = tv[j][s];
            Mi[(slot * TOPK + s) * 132 + c128] = (unsigned short)ti[j][s];
        }
    }
    __syncthreads();
    if (tid < 128) {
        float bv5[TOPK]; int bi5[TOPK];
#pragma unroll
        for (int s = 0; s < TOPK; ++s) { bv5[s] = -FLT_MAX; bi5[s] = 0; }
        for (int s = 0; s < 40; ++s) ins5(Mv[s * 132 + tid], (int)Mi[s * 132 + tid], bv5, bi5);
#pragma unroll
        for (int s = 0; s < TOPK; ++s) {
            const size_t o = ((size_t)(rslot * TOPK + s)) * NROWS + gcol0 + tid;
            pval[o] = bv5[s];
            pidx[o] = (unsigned short)bi5[s];
        }
    }
}

// ------------------------------------------------- 2b. SYMMETRIC gram MFMA, double-buffered staging
// grid (1225, 1, 4). K-loop now 2-phase: issue chunk cc+1 global_load_lds into
// the alternate 32KB buffer BEFORE computing chunk cc; ONE barrier per chunk
// (implicit vmcnt(0) at __syncthreads waits on the prefetch after compute).
__global__ __launch_bounds__(256, 2)
void gram_sym_kernel(const f16* __restrict__ Xs,
                     float* __restrict__ pval, unsigned short* __restrict__ pidx) {
    __shared__ __align__(16) char smem[65536];   // 2 x (As 16KB | Bs 16KB); TT/merge reuse low 33KB
    float* TT = (float*)smem;             // [128][65] transpose buffer (reused post-loop)

    const int tid = threadIdx.x;
    const int lane = tid & 63, wid = tid >> 6;
    const int wr = (wid >> 1) * 64, wc = (wid & 1) * 64;
    const int lm = lane & 15, q = lane >> 4;
    const int lm7 = lm & 7;
    const int b = blockIdx.z;

    // decode pair p -> (ri <= cj), p = cj*(cj+1)/2 + ri
    const int p = blockIdx.x;
    int cj = (int)((sqrtf(8.0f * (float)p + 1.0f) - 1.0f) * 0.5f);
    while ((cj + 1) * (cj + 2) / 2 <= p) ++cj;
    while (cj * (cj + 1) / 2 > p) --cj;
    const int ri = p - cj * (cj + 1) / 2;
    const int t0 = ri * 128, j0 = cj * 128;

    const size_t bbase = (size_t)b * THW;
    const f16* Xb = Xs + bbase * 512;

    const int srow = tid >> 3;
    const int skk = (((tid & 7) ^ (srow & 7)) * 8);

    int fj[4];
#pragma unroll
    for (int j = 0; j < 4; ++j) fj[j] = (j0 + wc + 16 * j + lm) / HW;

    float tv[4][TOPK];
    int   ti[4][TOPK];
#pragma unroll
    for (int j = 0; j < 4; ++j)
#pragma unroll
        for (int s = 0; s < TOPK; ++s) { tv[j][s] = -FLT_MAX; ti[j][s] = 0; }

    const int segA[3] = {0, 256, 0};
    const int segB[3] = {0, 0, 256};

    f32x4 acc[4][4];
#pragma unroll
    for (int i = 0; i < 4; ++i)
#pragma unroll
        for (int j = 0; j < 4; ++j) acc[i][j] = (f32x4)0.0f;

    // stage chunk cc into staging buffer bb (0/1)
    auto stage = [&](int cc, int bb) {
        const int seg = cc >> 2, k64 = (cc & 3) * 64;
        const int aoff = segA[seg] + k64 + skk;
        const int boff = segB[seg] + k64 + skk;
        char* dst = smem + bb * 32768;
#pragma unroll
        for (int pp = 0; pp < 4; ++pp)
            async16(Xb + (size_t)(t0 + srow + 32 * pp) * 512 + aoff,
                    dst + wid * 1024 + pp * 4096);
#pragma unroll
        for (int pp = 0; pp < 4; ++pp)
            async16(Xb + (size_t)(j0 + srow + 32 * pp) * 512 + boff,
                    dst + 16384 + wid * 1024 + pp * 4096);
    };

    stage(0, 0);
    __syncthreads();                          // drain prologue loads

    for (int cc = 0; cc < 12; ++cc) {
        const int bb = cc & 1;
        if (cc + 1 < 12) stage(cc + 1, bb ^ 1);   // prefetch flies under compute
        const f16* As = (const f16*)(smem + bb * 32768);
        const f16* Bs = As + 8192;
#pragma unroll
        for (int ks = 0; ks < 2; ++ks) {
            const int ku = (((4 * ks + q) ^ lm7) * 8);
            half8 av[4], bv[4];
#pragma unroll
            for (int i = 0; i < 4; ++i)
                av[i] = *(const half8*)(As + (wr + 16 * i + lm) * 64 + ku);
#pragma unroll
            for (int j = 0; j < 4; ++j)
                bv[j] = *(const half8*)(Bs + (wc + 16 * j + lm) * 64 + ku);
#pragma unroll
            for (int i = 0; i < 4; ++i)
#pragma unroll
                for (int j = 0; j < 4; ++j)
                    acc[i][j] = __builtin_amdgcn_mfma_f32_16x16x32_f16(av[i], bv[j], acc[i][j], 0, 0, 0);
        }
        __syncthreads();                      // waits prefetch (vmcnt) + readers done
    }

    // ---- normal side: columns in cj-tile, candidates t in ri-tile
#pragma unroll
    for (int i = 0; i < 4; ++i) {
        const int tb = t0 + wr + 16 * i + 4 * q;
#pragma unroll
        for (int reg = 0; reg < 4; ++reg) {
            const int t = tb + reg;
            const int ft = t / HW;
#pragma unroll
            for (int j = 0; j < 4; ++j) {
                const float key = acc[i][j][reg];
                if (ft != fj[j]) ins5(key, t, tv[j], ti[j]);
            }
        }
    }
    block_merge_store(tv, ti, smem, tid, wid, q, wc, lm,
                      ri, bbase + (size_t)j0, pval, pidx);

    // ---- transposed side: columns in ri-tile, candidates s in cj-tile
    if (ri != cj) {
        int fct[4];
#pragma unroll
        for (int j = 0; j < 4; ++j) fct[j] = (t0 + wc + 16 * j + lm) / HW;
        float tv2[4][TOPK];
        int   ti2[4][TOPK];
#pragma unroll
        for (int j = 0; j < 4; ++j)
#pragma unroll
            for (int s = 0; s < TOPK; ++s) { tv2[j][s] = -FLT_MAX; ti2[j][s] = 0; }
        const int wrb = wid >> 1;
#pragma unroll
        for (int h = 0; h < 2; ++h) {
            __syncthreads();             // previous smem readers done
            if ((wid & 1) == h) {        // waves holding s-half h write their acc
#pragma unroll
                for (int i = 0; i < 4; ++i)
#pragma unroll
                    for (int j = 0; j < 4; ++j)
#pragma unroll
                        for (int reg = 0; reg < 4; ++reg)
                            TT[(wr + 16 * i + 4 * q + reg) * 65 + 16 * j + lm] = acc[i][j][reg];
            }
            __syncthreads();
#pragma unroll
            for (int ii = 0; ii < 2; ++ii) {
                const int spb = wrb * 32 + 16 * ii + 4 * q;    // s-local within half
                const int sg0 = j0 + 64 * h + spb;             // global candidate col
#pragma unroll
                for (int reg = 0; reg < 4; ++reg) {
                    const int sg = sg0 + reg;
                    const int fs = sg / HW;
#pragma unroll
                    for (int j = 0; j < 4; ++j) {
                        const float key = TT[(wc + 16 * j + lm) * 65 + spb + reg];
                        if (fs != fct[j]) ins5(key, sg, tv2[j], ti2[j]);
                    }
                }
            }
        }
        block_merge_store(tv2, ti2, smem, tid, wid, q, wc, lm,
                          cj, bbase + (size_t)t0, pval, pidx);
    }
}

// ------------------------------------------------- 3. merge 49 tile-partials per column
__global__ __launch_bounds__(256)
void merge_topk_sym_kernel(const float* __restrict__ pval, const unsigned short* __restrict__ pidx,
                           int* __restrict__ idx5) {
    __shared__ float Lv[4][TOPK][64];
    __shared__ unsigned short Li[4][TOPK][64];
    const int tid = threadIdx.x;
    const int part = tid >> 6, cl = tid & 63;
    const int col = blockIdx.x * 64 + cl;

    float bv5[TOPK]; int bi5[TOPK];
#pragma unroll
    for (int s = 0; s < TOPK; ++s) { bv5[s] = -FLT_MAX; bi5[s] = 0; }

    const int r0 = part * 13;
    const int r1 = (r0 + 13 < NTILE) ? r0 + 13 : NTILE;
    for (int r = r0; r < r1; ++r) {
#pragma unroll
        for (int s = 0; s < TOPK; ++s) {
            const size_t o = ((size_t)(r * TOPK + s)) * NROWS + col;
            ins5(pval[o], (int)pidx[o], bv5, bi5);
        }
    }
#pragma unroll
    for (int s = 0; s < TOPK; ++s) { Lv[part][s][cl] = bv5[s]; Li[part][s][cl] = (unsigned short)bi5[s]; }
    __syncthreads();
    if (tid < 64) {
        float cv[TOPK]; int ci[TOPK];
#pragma unroll
        for (int s = 0; s < TOPK; ++s) { cv[s] = -FLT_MAX; ci[s] = 0; }
#pragma unroll
        for (int pp = 0; pp < 4; ++pp)
#pragma unroll
            for (int s = 0; s < TOPK; ++s) ins5(Lv[pp][s][tid], (int)Li[pp][s][tid], cv, ci);
        int* op = idx5 + (size_t)col * TOPK;
#pragma unroll
        for (int s = 0; s < TOPK; ++s) op[s] = ci[s];
    }
}

// ------------------------------------------------- 4. gather (normalized f16 pair * nrm) + max + BN partials
__global__ __launch_bounds__(256)
void gather_bn_kernel(const f16* __restrict__ Xs, const float* __restrict__ nrm,
                      const int* __restrict__ idx5,
                      f16* __restrict__ yf, float* __restrict__ partial) {
    __shared__ float ls[2][4][256];
    const int tid = threadIdx.x;
    const int wid = tid >> 6, lane = tid & 63;
    const int row0 = blockIdx.x * 32 + wid * 8;
    float s1x = 0, s1y = 0, s1z = 0, s1w = 0;
    float s2x = 0, s2y = 0, s2z = 0, s2w = 0;
    for (int rr = 0; rr < 8; ++rr) {
        const int row = row0 + rr;
        const int b = row / THW;
        const int* id = idx5 + (size_t)row * TOPK;
        const f16* base = Xs + (size_t)b * THW * 512;
        const float* nb = nrm + (size_t)b * THW;
        float4 m = make_float4(-FLT_MAX, -FLT_MAX, -FLT_MAX, -FLT_MAX);
#pragma unroll
        for (int i = 0; i < TOPK; ++i) {
            const int t = id[i];
            const float nv = nb[t];
            const f16* rp = base + (size_t)t * 512 + lane * 4;
            const half4 h = *(const half4*)rp;
            const half4 l = *(const half4*)(rp + 256);
            m.x = fmaxf(m.x, ((float)h.x + (float)l.x) * nv);
            m.y = fmaxf(m.y, ((float)h.y + (float)l.y) * nv);
            m.z = fmaxf(m.z, ((float)h.z + (float)l.z) * nv);
            m.w = fmaxf(m.w, ((float)h.w + (float)l.w) * nv);
        }
        half4 ym; ym.x = (f16)m.x; ym.y = (f16)m.y; ym.z = (f16)m.z; ym.w = (f16)m.w;
        *(half4*)(yf + (size_t)row * CCH + lane * 4) = ym;
        s1x += m.x; s1y += m.y; s1z += m.z; s1w += m.w;
        s2x += m.x * m.x; s2y += m.y * m.y; s2z += m.z * m.z; s2w += m.w * m.w;
    }
    *(float4*)&ls[0][wid][lane * 4] = make_float4(s1x, s1y, s1z, s1w);
    *(float4*)&ls[1][wid][lane * 4] = make_float4(s2x, s2y, s2z, s2w);
    __syncthreads();
    const float a  = ls[0][0][tid] + ls[0][1][tid] + ls[0][2][tid] + ls[0][3][tid];
    const float b2 = ls[1][0][tid] + ls[1][1][tid] + ls[1][2][tid] + ls[1][3][tid];
    partial[(size_t)blockIdx.x * 512 + tid] = a;
    partial[(size_t)blockIdx.x * 512 + 256 + tid] = b2;
}

// ------------------------------------------------- 5. BN finalize -> scale/shift
__global__ __launch_bounds__(256)
void bn_final_kernel(const float* __restrict__ partial, const float* __restrict__ gamma,
                     const float* __restrict__ beta, float* __restrict__ ab) {
    const int c = blockIdx.x;
    const int tid = threadIdx.x;
    float s1 = 0, s2 = 0;
    for (int p = tid; p < 784; p += 256) {
        s1 += partial[(size_t)p * 512 + c];
        s2 += partial[(size_t)p * 512 + 256 + c];
    }
    __shared__ float r1[256], r2[256];
    r1[tid] = s1; r2[tid] = s2;
    __syncthreads();
    for (int off = 128; off > 0; off >>= 1) {
        if (tid < off) { r1[tid] += r1[tid + off]; r2[tid] += r2[tid + off]; }
        __syncthreads();
    }
    if (tid == 0) {
        const float inv_n = 1.0f / 25088.0f;
        const float mean = r1[0] * inv_n;
        const float var  = r2[0] * inv_n - mean * mean;
        const float a = gamma[c] / sqrtf(var + 1e-5f);
        ab[c] = a;
        ab[256 + c] = beta[c] - mean * a;
    }
}

// ------------------------------------------------- 6. relu(BN) -> 1x1 conv (f16 MFMA) + identity
__global__ __launch_bounds__(256, 2)
void conv_f16_kernel(const f16* __restrict__ yf, const float* __restrict__ w,
                     const float* __restrict__ ab, const float* __restrict__ cb,
                     const float* __restrict__ x, float* __restrict__ out) {
    __shared__ __align__(16) f16 smem[2 * 128 * 64];
    f16* As = smem;
    f16* Ws = smem + 8192;

    const int tid = threadIdx.x;
    const int lane = tid & 63, wid = tid >> 6;
    const int wr = (wid >> 1) * 64, wc = (wid & 1) * 64;
    const int lm = lane & 15, q = lane >> 4;
    const int lm7 = lm & 7;
    const int R0 = blockIdx.x * 128;
    const int o0 = blockIdx.y * 128;
    const int g8 = (tid & 7) * 8;
    const int sr = tid >> 3;

    f32x4 acc[4][4];
#pragma unroll
    for (int i = 0; i < 4; ++i)
#pragma unroll
        for (int j = 0; j < 4; ++j) acc[i][j] = (f32x4)0.0f;

    float cbv[4];
#pragma unroll
    for (int j = 0; j < 4; ++j) cbv[j] = cb[o0 + wc + 16 * j + lm];

    for (int kc = 0; kc < CCH; kc += 64) {
        const int cbase = kc + g8;
        const float4 sa0 = *(const float4*)(ab + cbase);
        const float4 sa1 = *(const float4*)(ab + cbase + 4);
        const float4 sb0 = *(const float4*)(ab + 256 + cbase);
        const float4 sb1 = *(const float4*)(ab + 256 + cbase + 4);
#pragma unroll
        for (int p = 0; p < 4; ++p) {
            const int r = sr + 32 * p;
            const half8 hv = *(const half8*)(yf + (size_t)(R0 + r) * CCH + cbase);
            half8 z;
            z[0] = (f16)fmaxf(fmaf((float)hv[0], sa0.x, sb0.x), 0.0f);
            z[1] = (f16)fmaxf(fmaf((float)hv[1], sa0.y, sb0.y), 0.0f);
            z[2] = (f16)fmaxf(fmaf((float)hv[2], sa0.z, sb0.z), 0.0f);
            z[3] = (f16)fmaxf(fmaf((float)hv[3], sa0.w, sb0.w), 0.0f);
            z[4] = (f16)fmaxf(fmaf((float)hv[4], sa1.x, sb1.x), 0.0f);
            z[5] = (f16)fmaxf(fmaf((float)hv[5], sa1.y, sb1.y), 0.0f);
            z[6] = (f16)fmaxf(fmaf((float)hv[6], sa1.z, sb1.z), 0.0f);
            z[7] = (f16)fmaxf(fmaf((float)hv[7], sa1.w, sb1.w), 0.0f);
            *(half8*)(As + r * 64 + (((tid & 7) ^ (r & 7)) * 8)) = z;
        }
#pragma unroll
        for (int p = 0; p < 4; ++p) {
            const int ol = sr + 32 * p;
            const float4 w0 = *(const float4*)(w + (size_t)(o0 + ol) * CCH + cbase);
            const float4 w1 = *(const float4*)(w + (size_t)(o0 + ol) * CCH + cbase + 4);
            half8 z;
            z[0] = (f16)w0.x; z[1] = (f16)w0.y; z[2] = (f16)w0.z; z[3] = (f16)w0.w;
            z[4] = (f16)w1.x; z[5] = (f16)w1.y; z[6] = (f16)w1.z; z[7] = (f16)w1.w;
            *(half8*)(Ws + ol * 64 + (((tid & 7) ^ (ol & 7)) * 8)) = z;
        }
        __syncthreads();
#pragma unroll
        for (int ks = 0; ks < 2; ++ks) {
            const int ku = (((4 * ks + q) ^ lm7) * 8);
            half8 av[4], bv[4];
#pragma unroll
            for (int i = 0; i < 4; ++i)
                av[i] = *(const half8*)(As + (wr + 16 * i + lm) * 64 + ku);
#pragma unroll
            for (int j = 0; j < 4; ++j)
                bv[j] = *(const half8*)(Ws + (wc + 16 * j + lm) * 64 + ku);
#pragma unroll
            for (int i = 0; i < 4; ++i)
#pragma unroll
                for (int j = 0; j < 4; ++j)
                    acc[i][j] = __builtin_amdgcn_mfma_f32_16x16x32_f16(av[i], bv[j], acc[i][j], 0, 0, 0);
        }
        __syncthreads();
    }
#pragma unroll
    for (int i = 0; i < 4; ++i) {
#pragma unroll
        for (int reg = 0; reg < 4; ++reg) {
            const int R = R0 + wr + 16 * i + 4 * q + reg;
            const int bs = R / HW;
            const int hw = R - bs * HW;
#pragma unroll
            for (int j = 0; j < 4; ++j) {
                const int o = o0 + wc + 16 * j + lm;
                const size_t oi = ((size_t)bs * CCH + o) * HW + hw;
                out[oi] = acc[i][j][reg] + cbv[j] + x[oi];
            }
        }
    }
}

// ------------------------------------------------- launch
extern "C" void kernel_launch(void* const* d_in, const int* in_sizes, int n_in,
                              void* d_out, int out_size, void* d_ws, size_t ws_size,
                              hipStream_t stream) {
    const float* x      = (const float*)d_in[0];
    const float* gamma  = (const float*)d_in[1];
    const float* beta   = (const float*)d_in[2];
    const float* conv_w = (const float*)d_in[3];
    const float* conv_b = (const float*)d_in[4];
    float* out = (float*)d_out;

    float* ws = (float*)d_ws;
    f16*   Xsp  = (f16*)ws;                            // [25088][512] halves = 6,422,528 f
    f16*   yf   = (f16*)(ws + 6422528);                // [25088][256] halves = 3,211,264 f
    float* nrm  = ws + 9633792;                        // 25,088
    float* part = ws + 9658880;                        // 401,408
    float* ab   = ws + 10060288;                       // 512
    int*   idx5 = (int*)(ws + 10060800);               // 125,440 ints
    float* pvalS = ws + 10186240;                              // [49][5][25088] f32 SoA
    unsigned short* pidxS = (unsigned short*)(ws + 16332800);  // [49][5][25088] u16 SoA
    // total = 19,406,080 floats = 77.6 MB

    transpose_norm_split_kernel<<<dim3(32, 25), 256, 0, stream>>>(x, Xsp, nrm);
    gram_sym_kernel<<<dim3(NPAIR, 1, B_), 256, 0, stream>>>(Xsp, pvalS, pidxS);
    merge_topk_sym_kernel<<<NROWS / 64, 256, 0, stream>>>(pvalS, pidxS, idx5);
    gather_bn_kernel<<<NROWS / 32, 256, 0, stream>>>(Xsp, nrm, idx5, yf, part);
    bn_final_kernel<<<256, 256, 0, stream>>>(part, gamma, beta, ab);
    conv_f16_kernel<<<dim3(NROWS / 128, 2), 256, 0, stream>>>(yf, conv_w, ab, conv_b, x, out);
}

// Round 4
// 527.303 us; speedup vs baseline: 1.1077x; 1.1077x over previous
//
#include <hip/hip_runtime.h>
#include <cfloat>
#include <cmath>

#define B_    4
#define SNIP  8
#define CCH   256
#define HW    784
#define THW   6272      // SNIP*HW
#define NROWS 25088     // B_*THW
#define TOPK  5
#define NTILE 49        // 6272/128
#define NPAIR 1225      // 49*50/2

typedef _Float16 f16;
typedef f16   half8 __attribute__((ext_vector_type(8)));
typedef f16   half4 __attribute__((ext_vector_type(4)));
typedef float f32x4 __attribute__((ext_vector_type(4)));

// ---------------------------------------------------------------- utilities
__device__ __forceinline__ void ins5(float key, int idx, float tv[TOPK], int ti[TOPK]) {
    if (key > tv[4]) {
        if (key > tv[2]) {
            if (key > tv[1]) {
                tv[4] = tv[3]; ti[4] = ti[3];
                tv[3] = tv[2]; ti[3] = ti[2];
                tv[2] = tv[1]; ti[2] = ti[1];
                if (key > tv[0]) { tv[1] = tv[0]; ti[1] = ti[0]; tv[0] = key; ti[0] = idx; }
                else             { tv[1] = key;  ti[1] = idx; }
            } else {
                tv[4] = tv[3]; ti[4] = ti[3];
                tv[3] = tv[2]; ti[3] = ti[2];
                tv[2] = key;   ti[2] = idx;
            }
        } else {
            if (key > tv[3]) { tv[4] = tv[3]; ti[4] = ti[3]; tv[3] = key; ti[3] = idx; }
            else             { tv[4] = key;  ti[4] = idx; }
        }
    }
}

__device__ __forceinline__ void async16(const void* g, void* l) {
    __builtin_amdgcn_global_load_lds(
        (const __attribute__((address_space(1))) void*)g,
        (__attribute__((address_space(3))) void*)l, 16, 0, 0);
}

// rotated-transpose LDS address: [128][64] f32, bank = (row+col)%32 (conflict
// profile identical to +1-pad, but exactly 32KB so 5 blocks/CU fit)
__device__ __forceinline__ int tta(int row, int col) {
    return (row << 6) | ((col + row) & 63);
}

// ------------------------------------------------- 1. fused transpose + rownorm + NORMALIZED f16 split
__global__ __launch_bounds__(256)
void transpose_norm_split_kernel(const float* __restrict__ x, f16* __restrict__ Xs,
                                 float* __restrict__ nrm) {
    __shared__ float T[256][33];
    const int bs = blockIdx.x;
    const int p0 = blockIdx.y * 32;
    const int b = bs >> 3, f = bs & 7;
    const int tid = threadIdx.x;

    const int pl = tid & 31, ch = tid >> 5;
    const int p = p0 + pl;
    if (p < HW) {
#pragma unroll
        for (int cc = 0; cc < 32; ++cc) {
            const int c = cc * 8 + ch;
            T[c][pl] = x[((size_t)bs * CCH + c) * HW + p];
        }
    }
    __syncthreads();

    const int rloc = tid >> 3, k = tid & 7;
    const int gp = p0 + rloc;
    const size_t trow = (size_t)b * THW + (size_t)f * HW + gp;

    float s = 0.0f;
    if (gp < HW) {
#pragma unroll
        for (int j = 0; j < 32; ++j) {
            const float v = T[k * 32 + j][rloc];
            s += v * v;
        }
    }
    s += __shfl_xor(s, 1, 64);
    s += __shfl_xor(s, 2, 64);
    s += __shfl_xor(s, 4, 64);

    if (gp < HW) {
        const float sq = sqrtf(s);
        const float rs = 1.0f / sq;
        if (k == 0) nrm[trow] = sq;
#pragma unroll
        for (int q = 0; q < 4; ++q) {
            half8 hv, lv;
#pragma unroll
            for (int j = 0; j < 8; ++j) {
                const float v = T[k * 32 + q * 8 + j][rloc] * rs;
                const f16 h = (f16)v;
                hv[j] = h;
                lv[j] = (f16)(v - (float)h);
            }
            *(half8*)(Xs + trow * 512 + k * 32 + q * 8) = hv;
            *(half8*)(Xs + trow * 512 + 256 + k * 32 + q * 8) = lv;
        }
    }
}

// ------------------------------------------------- 2a. block-level top5 merge + SoA partial store
__device__ __forceinline__ void block_merge_store(
    const float (*tv)[TOPK], const int (*ti)[TOPK], char* smem,
    int tid, int wid, int q, int wc, int lm,
    int rslot, size_t gcol0,
    float* __restrict__ pval, unsigned short* __restrict__ pidx) {
    float* Mv = (float*)smem;                              // [40][132] f32 = 21120 B
    unsigned short* Mi = (unsigned short*)(smem + 21120);  // [40][132] u16 = 10560 B
    const int slot = (wid >> 1) * 4 + q;
    __syncthreads();                                       // previous smem use done
#pragma unroll
    for (int j = 0; j < 4; ++j) {
        const int c128 = wc + 16 * j + lm;
#pragma unroll
        for (int s = 0; s < TOPK; ++s) {
            Mv[(slot * TOPK + s) * 132 + c128] = tv[j][s];
            Mi[(slot * TOPK + s) * 132 + c128] = (unsigned short)ti[j][s];
        }
    }
    __syncthreads();
    if (tid < 128) {
        float bv5[TOPK]; int bi5[TOPK];
#pragma unroll
        for (int s = 0; s < TOPK; ++s) { bv5[s] = -FLT_MAX; bi5[s] = 0; }
        for (int s = 0; s < 40; ++s) ins5(Mv[s * 132 + tid], (int)Mi[s * 132 + tid], bv5, bi5);
#pragma unroll
        for (int s = 0; s < TOPK; ++s) {
            const size_t o = ((size_t)(rslot * TOPK + s)) * NROWS + gcol0 + tid;
            pval[o] = bv5[s];
            pidx[o] = (unsigned short)bi5[s];
        }
    }
}

// ------------------------------------------------- 2b. SYMMETRIC gram MFMA + dual top-5
// r2 K-loop structure (stage -> sync -> compute -> sync), 32KB LDS (5 blocks/CU),
// XCD-swizzled pair index for L2 tile residency, range-test frame masks.
__global__ __launch_bounds__(256, 3)
void gram_sym_kernel(const f16* __restrict__ Xs,
                     float* __restrict__ pval, unsigned short* __restrict__ pidx) {
    __shared__ __align__(16) char smem[32768];   // staging 32KB | TT rot [128][64] f32 | merge 31.7KB
    f16* As = (f16*)smem;                 // [128][64] halves, unit-swizzled
    f16* Bs = As + 8192;
    float* TT = (float*)smem;             // rotated transpose buffer (reused post-loop)

    const int tid = threadIdx.x;
    const int lane = tid & 63, wid = tid >> 6;
    const int wr = (wid >> 1) * 64, wc = (wid & 1) * 64;
    const int lm = lane & 15, q = lane >> 4;
    const int lm7 = lm & 7;
    const int b = blockIdx.z;

    // XCD-aware bijective swizzle: 1225 = 8*153 + 1; same-XCD blocks get a
    // contiguous pair-range -> shared cj B-tile stays resident in that XCD's L2.
    const int orig = blockIdx.x;
    const int xcd = orig & 7, idx8 = orig >> 3;
    const int p = (xcd == 0) ? idx8 : (154 + (xcd - 1) * 153 + idx8);

    // decode pair p -> (ri <= cj), p = cj*(cj+1)/2 + ri
    int cj = (int)((sqrtf(8.0f * (float)p + 1.0f) - 1.0f) * 0.5f);
    while ((cj + 1) * (cj + 2) / 2 <= p) ++cj;
    while (cj * (cj + 1) / 2 > p) --cj;
    const int ri = p - cj * (cj + 1) / 2;
    const int t0 = ri * 128, j0 = cj * 128;

    const size_t bbase = (size_t)b * THW;
    const f16* Xb = Xs + bbase * 512;

    const int srow = tid >> 3;
    const int skk = (((tid & 7) ^ (srow & 7)) * 8);

    // frame range of this thread's 4 output columns (normal side)
    int loj[4];
#pragma unroll
    for (int j = 0; j < 4; ++j) loj[j] = ((j0 + wc + 16 * j + lm) / HW) * HW;

    float tv[4][TOPK];
    int   ti[4][TOPK];
#pragma unroll
    for (int j = 0; j < 4; ++j)
#pragma unroll
        for (int s = 0; s < TOPK; ++s) { tv[j][s] = -FLT_MAX; ti[j][s] = 0; }

    const int segA[3] = {0, 256, 0};
    const int segB[3] = {0, 0, 256};

    f32x4 acc[4][4];
#pragma unroll
    for (int i = 0; i < 4; ++i)
#pragma unroll
        for (int j = 0; j < 4; ++j) acc[i][j] = (f32x4)0.0f;

    for (int cc = 0; cc < 12; ++cc) {
        const int seg = cc >> 2, k64 = (cc & 3) * 64;
        const int aoff = segA[seg] + k64 + skk;
        const int boff = segB[seg] + k64 + skk;
#pragma unroll
        for (int pp = 0; pp < 4; ++pp)
            async16(Xb + (size_t)(t0 + srow + 32 * pp) * 512 + aoff,
                    smem + wid * 1024 + pp * 4096);
#pragma unroll
        for (int pp = 0; pp < 4; ++pp)
            async16(Xb + (size_t)(j0 + srow + 32 * pp) * 512 + boff,
                    smem + 16384 + wid * 1024 + pp * 4096);
        __syncthreads();
#pragma unroll
        for (int ks = 0; ks < 2; ++ks) {
            const int ku = (((4 * ks + q) ^ lm7) * 8);
            half8 av[4], bv[4];
#pragma unroll
            for (int i = 0; i < 4; ++i)
                av[i] = *(const half8*)(As + (wr + 16 * i + lm) * 64 + ku);
#pragma unroll
            for (int j = 0; j < 4; ++j)
                bv[j] = *(const half8*)(Bs + (wc + 16 * j + lm) * 64 + ku);
#pragma unroll
            for (int i = 0; i < 4; ++i)
#pragma unroll
                for (int j = 0; j < 4; ++j)
                    acc[i][j] = __builtin_amdgcn_mfma_f32_16x16x32_f16(av[i], bv[j], acc[i][j], 0, 0, 0);
        }
        __syncthreads();
    }

    // ---- normal side: columns in cj-tile, candidates t in ri-tile
#pragma unroll
    for (int i = 0; i < 4; ++i) {
        const int tb = t0 + wr + 16 * i + 4 * q;
#pragma unroll
        for (int reg = 0; reg < 4; ++reg) {
            const int t = tb + reg;
#pragma unroll
            for (int j = 0; j < 4; ++j) {
                // same-frame -> key override to -FLT_MAX (never inserts)
                const float key = ((unsigned)(t - loj[j]) < (unsigned)HW)
                                  ? -FLT_MAX : acc[i][j][reg];
                ins5(key, t, tv[j], ti[j]);
            }
        }
    }
    block_merge_store(tv, ti, smem, tid, wid, q, wc, lm,
                      ri, bbase + (size_t)j0, pval, pidx);

    // ---- transposed side: columns in ri-tile, candidates s in cj-tile
    if (ri != cj) {
        int lo2[4];
#pragma unroll
        for (int j = 0; j < 4; ++j) lo2[j] = ((t0 + wc + 16 * j + lm) / HW) * HW;
        float tv2[4][TOPK];
        int   ti2[4][TOPK];
#pragma unroll
        for (int j = 0; j < 4; ++j)
#pragma unroll
            for (int s = 0; s < TOPK; ++s) { tv2[j][s] = -FLT_MAX; ti2[j][s] = 0; }
        const int wrb = wid >> 1;
#pragma unroll
        for (int h = 0; h < 2; ++h) {
            __syncthreads();             // previous smem readers done
            if ((wid & 1) == h) {        // waves holding s-half h write their acc
#pragma unroll
                for (int i = 0; i < 4; ++i)
#pragma unroll
                    for (int j = 0; j < 4; ++j)
#pragma unroll
                        for (int reg = 0; reg < 4; ++reg)
                            TT[tta(wr + 16 * i + 4 * q + reg, 16 * j + lm)] = acc[i][j][reg];
            }
            __syncthreads();
#pragma unroll
            for (int ii = 0; ii < 2; ++ii) {
                const int spb = wrb * 32 + 16 * ii + 4 * q;    // s-local within half
                const int sg0 = j0 + 64 * h + spb;             // global candidate col
#pragma unroll
                for (int reg = 0; reg < 4; ++reg) {
                    const int sg = sg0 + reg;
#pragma unroll
                    for (int j = 0; j < 4; ++j) {
                        const float raw = TT[tta(wc + 16 * j + lm, spb + reg)];
                        const float key = ((unsigned)(sg - lo2[j]) < (unsigned)HW)
                                          ? -FLT_MAX : raw;
                        ins5(key, sg, tv2[j], ti2[j]);
                    }
                }
            }
        }
        block_merge_store(tv2, ti2, smem, tid, wid, q, wc, lm,
                          cj, bbase + (size_t)t0, pval, pidx);
    }
}

// ------------------------------------------------- 3. merge 49 tile-partials per column
__global__ __launch_bounds__(256)
void merge_topk_sym_kernel(const float* __restrict__ pval, const unsigned short* __restrict__ pidx,
                           int* __restrict__ idx5) {
    __shared__ float Lv[4][TOPK][64];
    __shared__ unsigned short Li[4][TOPK][64];
    const int tid = threadIdx.x;
    const int part = tid >> 6, cl = tid & 63;
    const int col = blockIdx.x * 64 + cl;

    float bv5[TOPK]; int bi5[TOPK];
#pragma unroll
    for (int s = 0; s < TOPK; ++s) { bv5[s] = -FLT_MAX; bi5[s] = 0; }

    const int r0 = part * 13;
    const int r1 = (r0 + 13 < NTILE) ? r0 + 13 : NTILE;
    for (int r = r0; r < r1; ++r) {
#pragma unroll
        for (int s = 0; s < TOPK; ++s) {
            const size_t o = ((size_t)(r * TOPK + s)) * NROWS + col;
            ins5(pval[o], (int)pidx[o], bv5, bi5);
        }
    }
#pragma unroll
    for (int s = 0; s < TOPK; ++s) { Lv[part][s][cl] = bv5[s]; Li[part][s][cl] = (unsigned short)bi5[s]; }
    __syncthreads();
    if (tid < 64) {
        float cv[TOPK]; int ci[TOPK];
#pragma unroll
        for (int s = 0; s < TOPK; ++s) { cv[s] = -FLT_MAX; ci[s] = 0; }
#pragma unroll
        for (int pp = 0; pp < 4; ++pp)
#pragma unroll
            for (int s = 0; s < TOPK; ++s) ins5(Lv[pp][s][tid], (int)Li[pp][s][tid], cv, ci);
        int* op = idx5 + (size_t)col * TOPK;
#pragma unroll
        for (int s = 0; s < TOPK; ++s) op[s] = ci[s];
    }
}

// ------------------------------------------------- 4. gather (normalized f16 pair * nrm) + max + BN partials
__global__ __launch_bounds__(256)
void gather_bn_kernel(const f16* __restrict__ Xs, const float* __restrict__ nrm,
                      const int* __restrict__ idx5,
                      f16* __restrict__ yf, float* __restrict__ partial) {
    __shared__ float ls[2][4][256];
    const int tid = threadIdx.x;
    const int wid = tid >> 6, lane = tid & 63;
    const int row0 = blockIdx.x * 32 + wid * 8;
    float s1x = 0, s1y = 0, s1z = 0, s1w = 0;
    float s2x = 0, s2y = 0, s2z = 0, s2w = 0;
    for (int rr = 0; rr < 8; ++rr) {
        const int row = row0 + rr;
        const int b = row / THW;
        const int* id = idx5 + (size_t)row * TOPK;
        const f16* base = Xs + (size_t)b * THW * 512;
        const float* nb = nrm + (size_t)b * THW;
        float4 m = make_float4(-FLT_MAX, -FLT_MAX, -FLT_MAX, -FLT_MAX);
#pragma unroll
        for (int i = 0; i < TOPK; ++i) {
            const int t = id[i];
            const float nv = nb[t];
            const f16* rp = base + (size_t)t * 512 + lane * 4;
            const half4 h = *(const half4*)rp;
            const half4 l = *(const half4*)(rp + 256);
            m.x = fmaxf(m.x, ((float)h.x + (float)l.x) * nv);
            m.y = fmaxf(m.y, ((float)h.y + (float)l.y) * nv);
            m.z = fmaxf(m.z, ((float)h.z + (float)l.z) * nv);
            m.w = fmaxf(m.w, ((float)h.w + (float)l.w) * nv);
        }
        half4 ym; ym.x = (f16)m.x; ym.y = (f16)m.y; ym.z = (f16)m.z; ym.w = (f16)m.w;
        *(half4*)(yf + (size_t)row * CCH + lane * 4) = ym;
        s1x += m.x; s1y += m.y; s1z += m.z; s1w += m.w;
        s2x += m.x * m.x; s2y += m.y * m.y; s2z += m.z * m.z; s2w += m.w * m.w;
    }
    *(float4*)&ls[0][wid][lane * 4] = make_float4(s1x, s1y, s1z, s1w);
    *(float4*)&ls[1][wid][lane * 4] = make_float4(s2x, s2y, s2z, s2w);
    __syncthreads();
    const float a  = ls[0][0][tid] + ls[0][1][tid] + ls[0][2][tid] + ls[0][3][tid];
    const float b2 = ls[1][0][tid] + ls[1][1][tid] + ls[1][2][tid] + ls[1][3][tid];
    partial[(size_t)blockIdx.x * 512 + tid] = a;
    partial[(size_t)blockIdx.x * 512 + 256 + tid] = b2;
}

// ------------------------------------------------- 5. BN finalize -> scale/shift
__global__ __launch_bounds__(256)
void bn_final_kernel(const float* __restrict__ partial, const float* __restrict__ gamma,
                     const float* __restrict__ beta, float* __restrict__ ab) {
    const int c = blockIdx.x;
    const int tid = threadIdx.x;
    float s1 = 0, s2 = 0;
    for (int p = tid; p < 784; p += 256) {
        s1 += partial[(size_t)p * 512 + c];
        s2 += partial[(size_t)p * 512 + 256 + c];
    }
    __shared__ float r1[256], r2[256];
    r1[tid] = s1; r2[tid] = s2;
    __syncthreads();
    for (int off = 128; off > 0; off >>= 1) {
        if (tid < off) { r1[tid] += r1[tid + off]; r2[tid] += r2[tid + off]; }
        __syncthreads();
    }
    if (tid == 0) {
        const float inv_n = 1.0f / 25088.0f;
        const float mean = r1[0] * inv_n;
        const float var  = r2[0] * inv_n - mean * mean;
        const float a = gamma[c] / sqrtf(var + 1e-5f);
        ab[c] = a;
        ab[256 + c] = beta[c] - mean * a;
    }
}

// ------------------------------------------------- 6. relu(BN) -> 1x1 conv (f16 MFMA) + identity
__global__ __launch_bounds__(256, 2)
void conv_f16_kernel(const f16* __restrict__ yf, const float* __restrict__ w,
                     const float* __restrict__ ab, const float* __restrict__ cb,
                     const float* __restrict__ x, float* __restrict__ out) {
    __shared__ __align__(16) f16 smem[2 * 128 * 64];
    f16* As = smem;
    f16* Ws = smem + 8192;

    const int tid = threadIdx.x;
    const int lane = tid & 63, wid = tid >> 6;
    const int wr = (wid >> 1) * 64, wc = (wid & 1) * 64;
    const int lm = lane & 15, q = lane >> 4;
    const int lm7 = lm & 7;
    const int R0 = blockIdx.x * 128;
    const int o0 = blockIdx.y * 128;
    const int g8 = (tid & 7) * 8;
    const int sr = tid >> 3;

    f32x4 acc[4][4];
#pragma unroll
    for (int i = 0; i < 4; ++i)
#pragma unroll
        for (int j = 0; j < 4; ++j) acc[i][j] = (f32x4)0.0f;

    float cbv[4];
#pragma unroll
    for (int j = 0; j < 4; ++j) cbv[j] = cb[o0 + wc + 16 * j + lm];

    for (int kc = 0; kc < CCH; kc += 64) {
        const int cbase = kc + g8;
        const float4 sa0 = *(const float4*)(ab + cbase);
        const float4 sa1 = *(const float4*)(ab + cbase + 4);
        const float4 sb0 = *(const float4*)(ab + 256 + cbase);
        const float4 sb1 = *(const float4*)(ab + 256 + cbase + 4);
#pragma unroll
        for (int p = 0; p < 4; ++p) {
            const int r = sr + 32 * p;
            const half8 hv = *(const half8*)(yf + (size_t)(R0 + r) * CCH + cbase);
            half8 z;
            z[0] = (f16)fmaxf(fmaf((float)hv[0], sa0.x, sb0.x), 0.0f);
            z[1] = (f16)fmaxf(fmaf((float)hv[1], sa0.y, sb0.y), 0.0f);
            z[2] = (f16)fmaxf(fmaf((float)hv[2], sa0.z, sb0.z), 0.0f);
            z[3] = (f16)fmaxf(fmaf((float)hv[3], sa0.w, sb0.w), 0.0f);
            z[4] = (f16)fmaxf(fmaf((float)hv[4], sa1.x, sb1.x), 0.0f);
            z[5] = (f16)fmaxf(fmaf((float)hv[5], sa1.y, sb1.y), 0.0f);
            z[6] = (f16)fmaxf(fmaf((float)hv[6], sa1.z, sb1.z), 0.0f);
            z[7] = (f16)fmaxf(fmaf((float)hv[7], sa1.w, sb1.w), 0.0f);
            *(half8*)(As + r * 64 + (((tid & 7) ^ (r & 7)) * 8)) = z;
        }
#pragma unroll
        for (int p = 0; p < 4; ++p) {
            const int ol = sr + 32 * p;
            const float4 w0 = *(const float4*)(w + (size_t)(o0 + ol) * CCH + cbase);
            const float4 w1 = *(const float4*)(w + (size_t)(o0 + ol) * CCH + cbase + 4);
            half8 z;
            z[0] = (f16)w0.x; z[1] = (f16)w0.y; z[2] = (f16)w0.z; z[3] = (f16)w0.w;
            z[4] = (f16)w1.x; z[5] = (f16)w1.y; z[6] = (f16)w1.z; z[7] = (f16)w1.w;
            *(half8*)(Ws + ol * 64 + (((tid & 7) ^ (ol & 7)) * 8)) = z;
        }
        __syncthreads();
#pragma unroll
        for (int ks = 0; ks < 2; ++ks) {
            const int ku = (((4 * ks + q) ^ lm7) * 8);
            half8 av[4], bv[4];
#pragma unroll
            for (int i = 0; i < 4; ++i)
                av[i] = *(const half8*)(As + (wr + 16 * i + lm) * 64 + ku);
#pragma unroll
            for (int j = 0; j < 4; ++j)
                bv[j] = *(const half8*)(Ws + (wc + 16 * j + lm) * 64 + ku);
#pragma unroll
            for (int i = 0; i < 4; ++i)
#pragma unroll
                for (int j = 0; j < 4; ++j)
                    acc[i][j] = __builtin_amdgcn_mfma_f32_16x16x32_f16(av[i], bv[j], acc[i][j], 0, 0, 0);
        }
        __syncthreads();
    }
#pragma unroll
    for (int i = 0; i < 4; ++i) {
#pragma unroll
        for (int reg = 0; reg < 4; ++reg) {
            const int R = R0 + wr + 16 * i + 4 * q + reg;
            const int bs = R / HW;
            const int hw = R - bs * HW;
#pragma unroll
            for (int j = 0; j < 4; ++j) {
                const int o = o0 + wc + 16 * j + lm;
                const size_t oi = ((size_t)bs * CCH + o) * HW + hw;
                out[oi] = acc[i][j][reg] + cbv[j] + x[oi];
            }
        }
    }
}

// ------------------------------------------------- launch
extern "C" void kernel_launch(void* const* d_in, const int* in_sizes, int n_in,
                              void* d_out, int out_size, void* d_ws, size_t ws_size,
                              hipStream_t stream) {
    const float* x      = (const float*)d_in[0];
    const float* gamma  = (const float*)d_in[1];
    const float* beta   = (const float*)d_in[2];
    const float* conv_w = (const float*)d_in[3];
    const float* conv_b = (const float*)d_in[4];
    float* out = (float*)d_out;

    float* ws = (float*)d_ws;
    f16*   Xsp  = (f16*)ws;                            // [25088][512] halves = 6,422,528 f
    f16*   yf   = (f16*)(ws + 6422528);                // [25088][256] halves = 3,211,264 f
    float* nrm  = ws + 9633792;                        // 25,088
    float* part = ws + 9658880;                        // 401,408
    float* ab   = ws + 10060288;                       // 512
    int*   idx5 = (int*)(ws + 10060800);               // 125,440 ints
    float* pvalS = ws + 10186240;                              // [49][5][25088] f32 SoA
    unsigned short* pidxS = (unsigned short*)(ws + 16332800);  // [49][5][25088] u16 SoA
    // total = 19,406,080 floats = 77.6 MB

    transpose_norm_split_kernel<<<dim3(32, 25), 256, 0, stream>>>(x, Xsp, nrm);
    gram_sym_kernel<<<dim3(NPAIR, 1, B_), 256, 0, stream>>>(Xsp, pvalS, pidxS);
    merge_topk_sym_kernel<<<NROWS / 64, 256, 0, stream>>>(pvalS, pidxS, idx5);
    gather_bn_kernel<<<NROWS / 32, 256, 0, stream>>>(Xsp, nrm, idx5, yf, part);
    bn_final_kernel<<<256, 256, 0, stream>>>(part, gamma, beta, ab);
    conv_f16_kernel<<<dim3(NROWS / 128, 2), 256, 0, stream>>>(yf, conv_w, ab, conv_b, x, out);
}

// Round 5
// 418.758 us; speedup vs baseline: 1.3948x; 1.2592x over previous
//
#include <hip/hip_runtime.h>
#include <cfloat>
#include <cmath>

#define B_    4
#define SNIP  8
#define CCH   256
#define HW    784
#define THW   6272      // SNIP*HW
#define NROWS 25088     // B_*THW
#define TOPK  5
#define NTILE 49        // 6272/128
#define NPAIR 1225      // 49*50/2

typedef _Float16 f16;
typedef f16   half8 __attribute__((ext_vector_type(8)));
typedef f16   half4 __attribute__((ext_vector_type(4)));
typedef float f32x4 __attribute__((ext_vector_type(4)));

// ---------------------------------------------------------------- utilities
// Branchless sorted-5 insert: 5 v_cmp + cndmask chain, no divergence.
// Strict '>' so ties keep the earlier-inserted (lower-index) entry — same
// semantics as the branchy version. At wave level nearly every call had
// >=1 inserting lane, so the branchy form paid the full divergent union
// (~26 VALU + exec-mask churn) anyway; this is 23 VALU flat.
__device__ __forceinline__ void ins5(float key, int idx, float tv[TOPK], int ti[TOPK]) {
    const bool c4 = key > tv[4];
    const bool c3 = key > tv[3];
    const bool c2 = key > tv[2];
    const bool c1 = key > tv[1];
    const bool c0 = key > tv[0];
    tv[4] = c3 ? tv[3] : (c4 ? key : tv[4]);
    ti[4] = c3 ? ti[3] : (c4 ? idx : ti[4]);
    tv[3] = c2 ? tv[2] : (c3 ? key : tv[3]);
    ti[3] = c2 ? ti[2] : (c3 ? idx : ti[3]);
    tv[2] = c1 ? tv[1] : (c2 ? key : tv[2]);
    ti[2] = c1 ? ti[1] : (c2 ? idx : ti[2]);
    tv[1] = c0 ? tv[0] : (c1 ? key : tv[1]);
    ti[1] = c0 ? ti[0] : (c1 ? idx : ti[1]);
    tv[0] = c0 ? key  : tv[0];
    ti[0] = c0 ? idx  : ti[0];
}

__device__ __forceinline__ void async16(const void* g, void* l) {
    __builtin_amdgcn_global_load_lds(
        (const __attribute__((address_space(1))) void*)g,
        (__attribute__((address_space(3))) void*)l, 16, 0, 0);
}

// ------------------------------------------------- 1. fused transpose + rownorm + NORMALIZED f16 split
__global__ __launch_bounds__(256)
void transpose_norm_split_kernel(const float* __restrict__ x, f16* __restrict__ Xs,
                                 float* __restrict__ nrm) {
    __shared__ float T[256][33];
    const int bs = blockIdx.x;
    const int p0 = blockIdx.y * 32;
    const int b = bs >> 3, f = bs & 7;
    const int tid = threadIdx.x;

    const int pl = tid & 31, ch = tid >> 5;
    const int p = p0 + pl;
    if (p < HW) {
#pragma unroll
        for (int cc = 0; cc < 32; ++cc) {
            const int c = cc * 8 + ch;
            T[c][pl] = x[((size_t)bs * CCH + c) * HW + p];
        }
    }
    __syncthreads();

    const int rloc = tid >> 3, k = tid & 7;
    const int gp = p0 + rloc;
    const size_t trow = (size_t)b * THW + (size_t)f * HW + gp;

    float s = 0.0f;
    if (gp < HW) {
#pragma unroll
        for (int j = 0; j < 32; ++j) {
            const float v = T[k * 32 + j][rloc];
            s += v * v;
        }
    }
    s += __shfl_xor(s, 1, 64);
    s += __shfl_xor(s, 2, 64);
    s += __shfl_xor(s, 4, 64);

    if (gp < HW) {
        const float sq = sqrtf(s);
        const float rs = 1.0f / sq;
        if (k == 0) nrm[trow] = sq;
#pragma unroll
        for (int q = 0; q < 4; ++q) {
            half8 hv, lv;
#pragma unroll
            for (int j = 0; j < 8; ++j) {
                const float v = T[k * 32 + q * 8 + j][rloc] * rs;
                const f16 h = (f16)v;
                hv[j] = h;
                lv[j] = (f16)(v - (float)h);
            }
            *(half8*)(Xs + trow * 512 + k * 32 + q * 8) = hv;
            *(half8*)(Xs + trow * 512 + 256 + k * 32 + q * 8) = lv;
        }
    }
}

// ------------------------------------------------- 2a. block-level top5 merge + SoA partial store
__device__ __forceinline__ void block_merge_store(
    const float (*tv)[TOPK], const int (*ti)[TOPK], char* smem,
    int tid, int wid, int q, int wc, int lm,
    int rslot, size_t gcol0,
    float* __restrict__ pval, unsigned short* __restrict__ pidx) {
    float* Mv = (float*)smem;                              // [40][132] f32 = 21120 B
    unsigned short* Mi = (unsigned short*)(smem + 21120);  // [40][132] u16 = 10560 B
    const int slot = (wid >> 1) * 4 + q;
    __syncthreads();                                       // previous smem use done
#pragma unroll
    for (int j = 0; j < 4; ++j) {
        const int c128 = wc + 16 * j + lm;
#pragma unroll
        for (int s = 0; s < TOPK; ++s) {
            Mv[(slot * TOPK + s) * 132 + c128] = tv[j][s];
            Mi[(slot * TOPK + s) * 132 + c128] = (unsigned short)ti[j][s];
        }
    }
    __syncthreads();
    if (tid < 128) {
        float bv5[TOPK]; int bi5[TOPK];
#pragma unroll
        for (int s = 0; s < TOPK; ++s) { bv5[s] = -FLT_MAX; bi5[s] = 0; }
        for (int s = 0; s < 40; ++s) ins5(Mv[s * 132 + tid], (int)Mi[s * 132 + tid], bv5, bi5);
#pragma unroll
        for (int s = 0; s < TOPK; ++s) {
            const size_t o = ((size_t)(rslot * TOPK + s)) * NROWS + gcol0 + tid;
            pval[o] = bv5[s];
            pidx[o] = (unsigned short)bi5[s];
        }
    }
}

// ------------------------------------------------- 2b. SYMMETRIC gram MFMA + dual top-5
// r2 structure exactly (33280 LDS, no swizzle, 2-barrier K-loop); epilogue
// uses range-test frame masks folded into the key + branchless ins5.
__global__ __launch_bounds__(256, 3)
void gram_sym_kernel(const f16* __restrict__ Xs,
                     float* __restrict__ pval, unsigned short* __restrict__ pidx) {
    __shared__ __align__(16) char smem[33280];   // staging 32KB | TT [128][65] f32 | merge 31.7KB
    f16* As = (f16*)smem;                 // [128][64] halves, unit-swizzled
    f16* Bs = As + 8192;
    float* TT = (float*)smem;             // [128][65] transpose buffer (reused post-loop)

    const int tid = threadIdx.x;
    const int lane = tid & 63, wid = tid >> 6;
    const int wr = (wid >> 1) * 64, wc = (wid & 1) * 64;
    const int lm = lane & 15, q = lane >> 4;
    const int lm7 = lm & 7;
    const int b = blockIdx.z;

    // decode pair p -> (ri <= cj), p = cj*(cj+1)/2 + ri
    const int p = blockIdx.x;
    int cj = (int)((sqrtf(8.0f * (float)p + 1.0f) - 1.0f) * 0.5f);
    while ((cj + 1) * (cj + 2) / 2 <= p) ++cj;
    while (cj * (cj + 1) / 2 > p) --cj;
    const int ri = p - cj * (cj + 1) / 2;
    const int t0 = ri * 128, j0 = cj * 128;

    const size_t bbase = (size_t)b * THW;
    const f16* Xb = Xs + bbase * 512;

    const int srow = tid >> 3;
    const int skk = (((tid & 7) ^ (srow & 7)) * 8);

    // frame base of each of this thread's 4 output columns (normal side)
    int loj[4];
#pragma unroll
    for (int j = 0; j < 4; ++j) loj[j] = ((j0 + wc + 16 * j + lm) / HW) * HW;

    float tv[4][TOPK];
    int   ti[4][TOPK];
#pragma unroll
    for (int j = 0; j < 4; ++j)
#pragma unroll
        for (int s = 0; s < TOPK; ++s) { tv[j][s] = -FLT_MAX; ti[j][s] = 0; }

    const int segA[3] = {0, 256, 0};
    const int segB[3] = {0, 0, 256};

    f32x4 acc[4][4];
#pragma unroll
    for (int i = 0; i < 4; ++i)
#pragma unroll
        for (int j = 0; j < 4; ++j) acc[i][j] = (f32x4)0.0f;

    for (int cc = 0; cc < 12; ++cc) {
        const int seg = cc >> 2, k64 = (cc & 3) * 64;
        const int aoff = segA[seg] + k64 + skk;
        const int boff = segB[seg] + k64 + skk;
#pragma unroll
        for (int pp = 0; pp < 4; ++pp)
            async16(Xb + (size_t)(t0 + srow + 32 * pp) * 512 + aoff,
                    smem + wid * 1024 + pp * 4096);
#pragma unroll
        for (int pp = 0; pp < 4; ++pp)
            async16(Xb + (size_t)(j0 + srow + 32 * pp) * 512 + boff,
                    smem + 16384 + wid * 1024 + pp * 4096);
        __syncthreads();
#pragma unroll
        for (int ks = 0; ks < 2; ++ks) {
            const int ku = (((4 * ks + q) ^ lm7) * 8);
            half8 av[4], bv[4];
#pragma unroll
            for (int i = 0; i < 4; ++i)
                av[i] = *(const half8*)(As + (wr + 16 * i + lm) * 64 + ku);
#pragma unroll
            for (int j = 0; j < 4; ++j)
                bv[j] = *(const half8*)(Bs + (wc + 16 * j + lm) * 64 + ku);
#pragma unroll
            for (int i = 0; i < 4; ++i)
#pragma unroll
                for (int j = 0; j < 4; ++j)
                    acc[i][j] = __builtin_amdgcn_mfma_f32_16x16x32_f16(av[i], bv[j], acc[i][j], 0, 0, 0);
        }
        __syncthreads();
    }

    // ---- normal side: columns in cj-tile, candidates t in ri-tile
#pragma unroll
    for (int i = 0; i < 4; ++i) {
        const int tb = t0 + wr + 16 * i + 4 * q;
#pragma unroll
        for (int reg = 0; reg < 4; ++reg) {
            const int t = tb + reg;
#pragma unroll
            for (int j = 0; j < 4; ++j) {
                // same-frame -> key collapses to -FLT_MAX (never displaces)
                const float key = ((unsigned)(t - loj[j]) < (unsigned)HW)
                                  ? -FLT_MAX : acc[i][j][reg];
                ins5(key, t, tv[j], ti[j]);
            }
        }
    }
    block_merge_store(tv, ti, smem, tid, wid, q, wc, lm,
                      ri, bbase + (size_t)j0, pval, pidx);

    // ---- transposed side: columns in ri-tile, candidates s in cj-tile
    if (ri != cj) {
        int lo2[4];
#pragma unroll
        for (int j = 0; j < 4; ++j) lo2[j] = ((t0 + wc + 16 * j + lm) / HW) * HW;
        float tv2[4][TOPK];
        int   ti2[4][TOPK];
#pragma unroll
        for (int j = 0; j < 4; ++j)
#pragma unroll
            for (int s = 0; s < TOPK; ++s) { tv2[j][s] = -FLT_MAX; ti2[j][s] = 0; }
        const int wrb = wid >> 1;
#pragma unroll
        for (int h = 0; h < 2; ++h) {
            __syncthreads();             // previous smem readers done
            if ((wid & 1) == h) {        // waves holding s-half h write their acc
#pragma unroll
                for (int i = 0; i < 4; ++i)
#pragma unroll
                    for (int j = 0; j < 4; ++j)
#pragma unroll
                        for (int reg = 0; reg < 4; ++reg)
                            TT[(wr + 16 * i + 4 * q + reg) * 65 + 16 * j + lm] = acc[i][j][reg];
            }
            __syncthreads();
#pragma unroll
            for (int ii = 0; ii < 2; ++ii) {
                const int spb = wrb * 32 + 16 * ii + 4 * q;    // s-local within half
                const int sg0 = j0 + 64 * h + spb;             // global candidate col
#pragma unroll
                for (int reg = 0; reg < 4; ++reg) {
                    const int sg = sg0 + reg;
#pragma unroll
                    for (int j = 0; j < 4; ++j) {
                        const float raw = TT[(wc + 16 * j + lm) * 65 + spb + reg];
                        const float key = ((unsigned)(sg - lo2[j]) < (unsigned)HW)
                                          ? -FLT_MAX : raw;
                        ins5(key, sg, tv2[j], ti2[j]);
                    }
                }
            }
        }
        block_merge_store(tv2, ti2, smem, tid, wid, q, wc, lm,
                          cj, bbase + (size_t)t0, pval, pidx);
    }
}

// ------------------------------------------------- 3. merge 49 tile-partials per column
__global__ __launch_bounds__(256)
void merge_topk_sym_kernel(const float* __restrict__ pval, const unsigned short* __restrict__ pidx,
                           int* __restrict__ idx5) {
    __shared__ float Lv[4][TOPK][64];
    __shared__ unsigned short Li[4][TOPK][64];
    const int tid = threadIdx.x;
    const int part = tid >> 6, cl = tid & 63;
    const int col = blockIdx.x * 64 + cl;

    float bv5[TOPK]; int bi5[TOPK];
#pragma unroll
    for (int s = 0; s < TOPK; ++s) { bv5[s] = -FLT_MAX; bi5[s] = 0; }

    const int r0 = part * 13;
    const int r1 = (r0 + 13 < NTILE) ? r0 + 13 : NTILE;
    for (int r = r0; r < r1; ++r) {
#pragma unroll
        for (int s = 0; s < TOPK; ++s) {
            const size_t o = ((size_t)(r * TOPK + s)) * NROWS + col;
            ins5(pval[o], (int)pidx[o], bv5, bi5);
        }
    }
#pragma unroll
    for (int s = 0; s < TOPK; ++s) { Lv[part][s][cl] = bv5[s]; Li[part][s][cl] = (unsigned short)bi5[s]; }
    __syncthreads();
    if (tid < 64) {
        float cv[TOPK]; int ci[TOPK];
#pragma unroll
        for (int s = 0; s < TOPK; ++s) { cv[s] = -FLT_MAX; ci[s] = 0; }
#pragma unroll
        for (int pp = 0; pp < 4; ++pp)
#pragma unroll
            for (int s = 0; s < TOPK; ++s) ins5(Lv[pp][s][tid], (int)Li[pp][s][tid], cv, ci);
        int* op = idx5 + (size_t)col * TOPK;
#pragma unroll
        for (int s = 0; s < TOPK; ++s) op[s] = ci[s];
    }
}

// ------------------------------------------------- 4. gather (normalized f16 pair * nrm) + max + BN partials
__global__ __launch_bounds__(256)
void gather_bn_kernel(const f16* __restrict__ Xs, const float* __restrict__ nrm,
                      const int* __restrict__ idx5,
                      f16* __restrict__ yf, float* __restrict__ partial) {
    __shared__ float ls[2][4][256];
    const int tid = threadIdx.x;
    const int wid = tid >> 6, lane = tid & 63;
    const int row0 = blockIdx.x * 32 + wid * 8;
    float s1x = 0, s1y = 0, s1z = 0, s1w = 0;
    float s2x = 0, s2y = 0, s2z = 0, s2w = 0;
    for (int rr = 0; rr < 8; ++rr) {
        const int row = row0 + rr;
        const int b = row / THW;
        const int* id = idx5 + (size_t)row * TOPK;
        const f16* base = Xs + (size_t)b * THW * 512;
        const float* nb = nrm + (size_t)b * THW;
        float4 m = make_float4(-FLT_MAX, -FLT_MAX, -FLT_MAX, -FLT_MAX);
#pragma unroll
        for (int i = 0; i < TOPK; ++i) {
            const int t = id[i];
            const float nv = nb[t];
            const f16* rp = base + (size_t)t * 512 + lane * 4;
            const half4 h = *(const half4*)rp;
            const half4 l = *(const half4*)(rp + 256);
            m.x = fmaxf(m.x, ((float)h.x + (float)l.x) * nv);
            m.y = fmaxf(m.y, ((float)h.y + (float)l.y) * nv);
            m.z = fmaxf(m.z, ((float)h.z + (float)l.z) * nv);
            m.w = fmaxf(m.w, ((float)h.w + (float)l.w) * nv);
        }
        half4 ym; ym.x = (f16)m.x; ym.y = (f16)m.y; ym.z = (f16)m.z; ym.w = (f16)m.w;
        *(half4*)(yf + (size_t)row * CCH + lane * 4) = ym;
        s1x += m.x; s1y += m.y; s1z += m.z; s1w += m.w;
        s2x += m.x * m.x; s2y += m.y * m.y; s2z += m.z * m.z; s2w += m.w * m.w;
    }
    *(float4*)&ls[0][wid][lane * 4] = make_float4(s1x, s1y, s1z, s1w);
    *(float4*)&ls[1][wid][lane * 4] = make_float4(s2x, s2y, s2z, s2w);
    __syncthreads();
    const float a  = ls[0][0][tid] + ls[0][1][tid] + ls[0][2][tid] + ls[0][3][tid];
    const float b2 = ls[1][0][tid] + ls[1][1][tid] + ls[1][2][tid] + ls[1][3][tid];
    partial[(size_t)blockIdx.x * 512 + tid] = a;
    partial[(size_t)blockIdx.x * 512 + 256 + tid] = b2;
}

// ------------------------------------------------- 5. BN finalize -> scale/shift
__global__ __launch_bounds__(256)
void bn_final_kernel(const float* __restrict__ partial, const float* __restrict__ gamma,
                     const float* __restrict__ beta, float* __restrict__ ab) {
    const int c = blockIdx.x;
    const int tid = threadIdx.x;
    float s1 = 0, s2 = 0;
    for (int p = tid; p < 784; p += 256) {
        s1 += partial[(size_t)p * 512 + c];
        s2 += partial[(size_t)p * 512 + 256 + c];
    }
    __shared__ float r1[256], r2[256];
    r1[tid] = s1; r2[tid] = s2;
    __syncthreads();
    for (int off = 128; off > 0; off >>= 1) {
        if (tid < off) { r1[tid] += r1[tid + off]; r2[tid] += r2[tid + off]; }
        __syncthreads();
    }
    if (tid == 0) {
        const float inv_n = 1.0f / 25088.0f;
        const float mean = r1[0] * inv_n;
        const float var  = r2[0] * inv_n - mean * mean;
        const float a = gamma[c] / sqrtf(var + 1e-5f);
        ab[c] = a;
        ab[256 + c] = beta[c] - mean * a;
    }
}

// ------------------------------------------------- 6. relu(BN) -> 1x1 conv (f16 MFMA) + identity
__global__ __launch_bounds__(256, 2)
void conv_f16_kernel(const f16* __restrict__ yf, const float* __restrict__ w,
                     const float* __restrict__ ab, const float* __restrict__ cb,
                     const float* __restrict__ x, float* __restrict__ out) {
    __shared__ __align__(16) f16 smem[2 * 128 * 64];
    f16* As = smem;
    f16* Ws = smem + 8192;

    const int tid = threadIdx.x;
    const int lane = tid & 63, wid = tid >> 6;
    const int wr = (wid >> 1) * 64, wc = (wid & 1) * 64;
    const int lm = lane & 15, q = lane >> 4;
    const int lm7 = lm & 7;
    const int R0 = blockIdx.x * 128;
    const int o0 = blockIdx.y * 128;
    const int g8 = (tid & 7) * 8;
    const int sr = tid >> 3;

    f32x4 acc[4][4];
#pragma unroll
    for (int i = 0; i < 4; ++i)
#pragma unroll
        for (int j = 0; j < 4; ++j) acc[i][j] = (f32x4)0.0f;

    float cbv[4];
#pragma unroll
    for (int j = 0; j < 4; ++j) cbv[j] = cb[o0 + wc + 16 * j + lm];

    for (int kc = 0; kc < CCH; kc += 64) {
        const int cbase = kc + g8;
        const float4 sa0 = *(const float4*)(ab + cbase);
        const float4 sa1 = *(const float4*)(ab + cbase + 4);
        const float4 sb0 = *(const float4*)(ab + 256 + cbase);
        const float4 sb1 = *(const float4*)(ab + 256 + cbase + 4);
#pragma unroll
        for (int p = 0; p < 4; ++p) {
            const int r = sr + 32 * p;
            const half8 hv = *(const half8*)(yf + (size_t)(R0 + r) * CCH + cbase);
            half8 z;
            z[0] = (f16)fmaxf(fmaf((float)hv[0], sa0.x, sb0.x), 0.0f);
            z[1] = (f16)fmaxf(fmaf((float)hv[1], sa0.y, sb0.y), 0.0f);
            z[2] = (f16)fmaxf(fmaf((float)hv[2], sa0.z, sb0.z), 0.0f);
            z[3] = (f16)fmaxf(fmaf((float)hv[3], sa0.w, sb0.w), 0.0f);
            z[4] = (f16)fmaxf(fmaf((float)hv[4], sa1.x, sb1.x), 0.0f);
            z[5] = (f16)fmaxf(fmaf((float)hv[5], sa1.y, sb1.y), 0.0f);
            z[6] = (f16)fmaxf(fmaf((float)hv[6], sa1.z, sb1.z), 0.0f);
            z[7] = (f16)fmaxf(fmaf((float)hv[7], sa1.w, sb1.w), 0.0f);
            *(half8*)(As + r * 64 + (((tid & 7) ^ (r & 7)) * 8)) = z;
        }
#pragma unroll
        for (int p = 0; p < 4; ++p) {
            const int ol = sr + 32 * p;
            const float4 w0 = *(const float4*)(w + (size_t)(o0 + ol) * CCH + cbase);
            const float4 w1 = *(const float4*)(w + (size_t)(o0 + ol) * CCH + cbase + 4);
            half8 z;
            z[0] = (f16)w0.x; z[1] = (f16)w0.y; z[2] = (f16)w0.z; z[3] = (f16)w0.w;
            z[4] = (f16)w1.x; z[5] = (f16)w1.y; z[6] = (f16)w1.z; z[7] = (f16)w1.w;
            *(half8*)(Ws + ol * 64 + (((tid & 7) ^ (ol & 7)) * 8)) = z;
        }
        __syncthreads();
#pragma unroll
        for (int ks = 0; ks < 2; ++ks) {
            const int ku = (((4 * ks + q) ^ lm7) * 8);
            half8 av[4], bv[4];
#pragma unroll
            for (int i = 0; i < 4; ++i)
                av[i] = *(const half8*)(As + (wr + 16 * i + lm) * 64 + ku);
#pragma unroll
            for (int j = 0; j < 4; ++j)
                bv[j] = *(const half8*)(Ws + (wc + 16 * j + lm) * 64 + ku);
#pragma unroll
            for (int i = 0; i < 4; ++i)
#pragma unroll
                for (int j = 0; j < 4; ++j)
                    acc[i][j] = __builtin_amdgcn_mfma_f32_16x16x32_f16(av[i], bv[j], acc[i][j], 0, 0, 0);
        }
        __syncthreads();
    }
#pragma unroll
    for (int i = 0; i < 4; ++i) {
#pragma unroll
        for (int reg = 0; reg < 4; ++reg) {
            const int R = R0 + wr + 16 * i + 4 * q + reg;
            const int bs = R / HW;
            const int hw = R - bs * HW;
#pragma unroll
            for (int j = 0; j < 4; ++j) {
                const int o = o0 + wc + 16 * j + lm;
                const size_t oi = ((size_t)bs * CCH + o) * HW + hw;
                out[oi] = acc[i][j][reg] + cbv[j] + x[oi];
            }
        }
    }
}

// ------------------------------------------------- launch
extern "C" void kernel_launch(void* const* d_in, const int* in_sizes, int n_in,
                              void* d_out, int out_size, void* d_ws, size_t ws_size,
                              hipStream_t stream) {
    const float* x      = (const float*)d_in[0];
    const float* gamma  = (const float*)d_in[1];
    const float* beta   = (const float*)d_in[2];
    const float* conv_w = (const float*)d_in[3];
    const float* conv_b = (const float*)d_in[4];
    float* out = (float*)d_out;

    float* ws = (float*)d_ws;
    f16*   Xsp  = (f16*)ws;                            // [25088][512] halves = 6,422,528 f
    f16*   yf   = (f16*)(ws + 6422528);                // [25088][256] halves = 3,211,264 f
    float* nrm  = ws + 9633792;                        // 25,088
    float* part = ws + 9658880;                        // 401,408
    float* ab   = ws + 10060288;                       // 512
    int*   idx5 = (int*)(ws + 10060800);               // 125,440 ints
    float* pvalS = ws + 10186240;                              // [49][5][25088] f32 SoA
    unsigned short* pidxS = (unsigned short*)(ws + 16332800);  // [49][5][25088] u16 SoA
    // total = 19,406,080 floats = 77.6 MB

    transpose_norm_split_kernel<<<dim3(32, 25), 256, 0, stream>>>(x, Xsp, nrm);
    gram_sym_kernel<<<dim3(NPAIR, 1, B_), 256, 0, stream>>>(Xsp, pvalS, pidxS);
    merge_topk_sym_kernel<<<NROWS / 64, 256, 0, stream>>>(pvalS, pidxS, idx5);
    gather_bn_kernel<<<NROWS / 32, 256, 0, stream>>>(Xsp, nrm, idx5, yf, part);
    bn_final_kernel<<<256, 256, 0, stream>>>(part, gamma, beta, ab);
    conv_f16_kernel<<<dim3(NROWS / 128, 2), 256, 0, stream>>>(yf, conv_w, ab, conv_b, x, out);
}